// Round 6
// baseline (281.915 us; speedup 1.0000x reference)
//
#include <hip/hip_runtime.h>
#include <hip/hip_bf16.h>
#include <hip/hip_fp16.h>

// GCN: x1 = relu(scatter(norm * (X@W1)[src] -> dst) + b1)
//      x2 = relu(scatter(norm * (x1@W2)[src] -> dst) + b2)
//      out = meanpool_by_graph(x2) @ Wlin + blin
// Factored norm: out[d] = dis[d]*(sum_{s in N(d)} h'[s] + h'[d]) + b,
// where h' = (X@W) row-scaled by dis (GEMM epilogue, fp16 stored).
// CSR via 2-pass LDS-write-combined bucket sort. Layer-2 aggregate fused
// with mean-pool partial sums (atomic fp32 into partial[NG][F]).
constexpr int NN = 100000;   // nodes
constexpr int NE = 1600000;  // edges
constexpr int NG = 512;      // graphs
constexpr int F  = 128;      // feature dim (in == hidden)

constexpr int NB   = 392;    // buckets: node bucket = dst >> 8
constexpr int RCAP = 4608;   // per-bucket region capacity (Poisson(4082) + 8 sigma)
constexpr int CAP  = 32;     // LDS staging entries per bucket

typedef _Float16 f16;
typedef f16 f16x2 __attribute__((ext_vector_type(2)));
typedef f16 f16x4 __attribute__((ext_vector_type(4)));
typedef f16 f16x8 __attribute__((ext_vector_type(8)));
typedef float f32x4 __attribute__((ext_vector_type(4)));
typedef unsigned int u32;
typedef u32 u32x4a __attribute__((ext_vector_type(4), aligned(4)));

// ---------------- W prep (+ cursor init): fp32 [k][n] -> fp16 [n][k] ----------------
__global__ void prep_w(const float* __restrict__ W1, const float* __restrict__ W2,
                       f16* __restrict__ WT1, f16* __restrict__ WT2,
                       int* __restrict__ gcur) {
    int idx = blockIdx.x * blockDim.x + threadIdx.x;
    if (idx < NB) gcur[idx] = idx * RCAP;
    if (idx < 128 * 128) {
        int n = idx >> 7, k = idx & 127;
        WT1[idx] = (f16)W1[k * 128 + n];
        WT2[idx] = (f16)W2[k * 128 + n];
    }
}

// ---------------- pass 1: bin edges by dst bucket, LDS write-combining ----------------
__global__ __launch_bounds__(256) void bin_edges(const int* __restrict__ ei,
                                                 int* __restrict__ gcur,
                                                 u32* __restrict__ binned) {
    __shared__ u32 stage[NB][CAP];   // 50 KB
    __shared__ int scnt[NB];
    for (int b = threadIdx.x; b < NB; b += 256) scnt[b] = 0;
    __syncthreads();
    const int per = NE / 256;        // 6250
    const int e0 = blockIdx.x * per;
    for (int r = 0; r < per; r += 256) {
        int k = r + threadIdx.x;
        if (k < per) {
            int e = e0 + k;
            int s = __builtin_nontemporal_load(&ei[e]);
            int d = __builtin_nontemporal_load(&ei[NE + e]);
            int b = d >> 8;
            u32 v = ((u32)(d & 255) << 24) | (u32)s;
            int p = atomicAdd(&scnt[b], 1);
            if (p < CAP) stage[b][p] = v;   // overflow P ~ 1e-18
        }
        __syncthreads();
        for (int b2 = threadIdx.x; b2 < NB; b2 += 256) {
            int n = scnt[b2];
            if (n >= 16) {
                int f = n & ~15;
                int base = atomicAdd(&gcur[b2], f);
                const u32x4a* st4 = (const u32x4a*)&stage[b2][0];
                u32x4a* out4 = (u32x4a*)&binned[base];
                for (int j = 0; j < (f >> 2); j++) out4[j] = st4[j];
                for (int j = 0; j < n - f; j++) stage[b2][j] = stage[b2][f + j];
                scnt[b2] = n - f;
            }
        }
        __syncthreads();
    }
    for (int b2 = threadIdx.x; b2 < NB; b2 += 256) {
        int n = scnt[b2];
        if (n > 0) {
            int base = atomicAdd(&gcur[b2], n);
            for (int j = 0; j < n; j++) binned[base + j] = stage[b2][j];
        }
    }
}

// ---------------- pass 1.5: scan bucket counts -> bucket bases ----------------
__global__ void scan_buckets(const int* __restrict__ gcur, int* __restrict__ bucketBase,
                             int* __restrict__ offs) {
    __shared__ int tmp[512];
    int t = threadIdx.x;
    int c = (t < NB) ? (gcur[t] - t * RCAP) : 0;
    tmp[t] = c;
    __syncthreads();
    for (int d = 1; d < 512; d <<= 1) {
        int x = (t >= d) ? tmp[t - d] : 0;
        __syncthreads();
        tmp[t] += x;
        __syncthreads();
    }
    if (t < NB) bucketBase[t] = tmp[t] - c;
    if (t == 0) offs[NN] = NE;
}

// ---------------- pass 2: per-bucket local CSR in LDS -> coalesced writeout ----------------
__global__ __launch_bounds__(256) void build_csr(const u32* __restrict__ binned,
                                                 const int* __restrict__ gcur,
                                                 const int* __restrict__ bucketBase,
                                                 int* __restrict__ offs,
                                                 float* __restrict__ dis,
                                                 int* __restrict__ csr_src) {
    __shared__ u32 ed[RCAP];
    __shared__ u32 lcsr[RCAP];
    __shared__ int hist[256];
    __shared__ int loff[256];
    __shared__ int lcur[256];
    const int b = blockIdx.x;
    int cnt = gcur[b] - b * RCAP;
    if (cnt > RCAP) cnt = RCAP;
    const int gbase = bucketBase[b];
    const int t = threadIdx.x;
    hist[t] = 0;
    __syncthreads();
    for (int j = t; j < cnt; j += 256) {
        u32 v = __builtin_nontemporal_load(&binned[(size_t)b * RCAP + j]);
        ed[j] = v;
        atomicAdd(&hist[v >> 24], 1);
    }
    __syncthreads();
    int h = hist[t];
    loff[t] = h;
    __syncthreads();
    for (int d = 1; d < 256; d <<= 1) {
        int x = (t >= d) ? loff[t - d] : 0;
        __syncthreads();
        loff[t] += x;
        __syncthreads();
    }
    int excl = loff[t] - h;
    lcur[t] = excl;
    int node = (b << 8) + t;
    if (node < NN) {
        offs[node] = gbase + excl;
        dis[node] = rsqrtf((float)(h + 1));   // +1 self-loop
    }
    __syncthreads();
    for (int j = t; j < cnt; j += 256) {
        u32 v = ed[j];
        int p = atomicAdd(&lcur[v >> 24], 1);
        lcsr[p] = v & 0x1FFFFu;
    }
    __syncthreads();
    for (int j = t; j < cnt; j += 256) csr_src[gbase + j] = (int)lcsr[j];
}

// ---------------- MFMA fp16 GEMM: H[M,128] = (X[M,128] @ W[128,128]) * dis[row] ----------------
template<bool IN_HALF>
__global__ __launch_bounds__(256) void gemm_mfma(const void* __restrict__ Xv,
                                                 const f16* __restrict__ WT,  // [n][k] fp16
                                                 const float* __restrict__ dis,
                                                 f16* __restrict__ H, int M) {
    __shared__ f16 sX[128 * 136];
    __shared__ f16 sW[128 * 136];
    const int tid = threadIdx.x;
    const int row0 = blockIdx.x * 128;
    {   // stage W^T: [n][k]
        const f16x8* Wg = (const f16x8*)WT;
        #pragma unroll
        for (int i = 0; i < 8; i++) {
            int idx = tid + 256 * i;
            int n = idx >> 4, kc = idx & 15;
            *(f16x8*)&sW[n * 136 + kc * 8] = Wg[idx];
        }
    }
    if (IN_HALF) {
        const f16x8* Xg = (const f16x8*)Xv;
        #pragma unroll
        for (int i = 0; i < 8; i++) {
            int idx = tid + 256 * i;
            int r = idx >> 4, kc = idx & 15;
            f16x8 v = {};
            if (row0 + r < M) v = Xg[(size_t)(row0 + r) * 16 + kc];
            *(f16x8*)&sX[r * 136 + kc * 8] = v;
        }
    } else {
        const float4* Xg = (const float4*)Xv;
        #pragma unroll
        for (int i = 0; i < 16; i++) {
            int idx = tid + 256 * i;
            int r = idx >> 5, c4 = idx & 31;
            float4 v = make_float4(0.f, 0.f, 0.f, 0.f);
            if (row0 + r < M) v = Xg[(size_t)(row0 + r) * 32 + c4];
            f16x4 hv = {(f16)v.x, (f16)v.y, (f16)v.z, (f16)v.w};
            *(f16x4*)&sX[r * 136 + c4 * 4] = hv;
        }
    }
    __syncthreads();

    const int wid = tid >> 6;
    const int lane = tid & 63;
    const int wrow = wid * 32;
    const int lr = lane & 15;
    const int lk = (lane >> 4) * 8;
    f32x4 acc[2][8] = {};
    #pragma unroll
    for (int ks = 0; ks < 4; ks++) {
        f16x8 a[2], b[8];
        #pragma unroll
        for (int mf = 0; mf < 2; mf++)
            a[mf] = *(const f16x8*)&sX[(wrow + mf * 16 + lr) * 136 + ks * 32 + lk];
        #pragma unroll
        for (int nf = 0; nf < 8; nf++)
            b[nf] = *(const f16x8*)&sW[(nf * 16 + lr) * 136 + ks * 32 + lk];
        #pragma unroll
        for (int mf = 0; mf < 2; mf++)
            #pragma unroll
            for (int nf = 0; nf < 8; nf++)
                acc[mf][nf] = __builtin_amdgcn_mfma_f32_16x16x32_f16(a[mf], b[nf], acc[mf][nf], 0, 0, 0);
    }
    // C layout: col = lane&15, row = (lane>>4)*4 + reg
    const int crow = (lane >> 4) * 4;
    #pragma unroll
    for (int mf = 0; mf < 2; mf++) {
        #pragma unroll
        for (int reg = 0; reg < 4; reg++) {
            int row = row0 + wrow + mf * 16 + crow + reg;
            if (row < M) {
                float sc = dis[row];
                #pragma unroll
                for (int nf = 0; nf < 8; nf++)
                    H[(size_t)row * 128 + nf * 16 + lr] = (f16)(acc[mf][nf][reg] * sc);
            }
        }
    }
}

// ---------------- gather core: sum of neighbor rows (quarter-wave layout) ----------------
// Returns per-lane acc[8]; quarter q handles edges t=s+q, s+q+4, ...; lane r
// reads 16 B chunk r. Unroll-4 => 16 rows in flight per wave.
__device__ __forceinline__ void gather_rows(const f16* __restrict__ h, int i,
                                            const int* __restrict__ offs,
                                            const int* __restrict__ csr_src,
                                            int q, int r, float acc[8]) {
    if (q == 0) {  // self-loop
        f16x8 v = *(const f16x8*)(h + (size_t)i * F + r * 8);
        #pragma unroll
        for (int j = 0; j < 8; j++) acc[j] = (float)v[j];
    }
    const int s = offs[i], e = offs[i + 1];
    int t = s + q;
    for (; t + 12 < e; t += 16) {
        int sr0 = __builtin_nontemporal_load(&csr_src[t]);
        int sr1 = __builtin_nontemporal_load(&csr_src[t + 4]);
        int sr2 = __builtin_nontemporal_load(&csr_src[t + 8]);
        int sr3 = __builtin_nontemporal_load(&csr_src[t + 12]);
        f16x8 v0 = *(const f16x8*)(h + (size_t)sr0 * F + r * 8);
        f16x8 v1 = *(const f16x8*)(h + (size_t)sr1 * F + r * 8);
        f16x8 v2 = *(const f16x8*)(h + (size_t)sr2 * F + r * 8);
        f16x8 v3 = *(const f16x8*)(h + (size_t)sr3 * F + r * 8);
        #pragma unroll
        for (int j = 0; j < 8; j++)
            acc[j] += ((float)v0[j] + (float)v1[j]) + ((float)v2[j] + (float)v3[j]);
    }
    for (; t < e; t += 4) {
        int sr = __builtin_nontemporal_load(&csr_src[t]);
        f16x8 v = *(const f16x8*)(h + (size_t)sr * F + r * 8);
        #pragma unroll
        for (int j = 0; j < 8; j++) acc[j] += (float)v[j];
    }
    #pragma unroll
    for (int j = 0; j < 8; j++) {
        acc[j] += __shfl_xor(acc[j], 16);
        acc[j] += __shfl_xor(acc[j], 32);
    }
}

// ---------------- layer-1 aggregate: scale + bias + relu -> fp16 out ----------------
__global__ __launch_bounds__(256) void aggregate16(const f16* __restrict__ h,
                                                   const int* __restrict__ offs,
                                                   const int* __restrict__ csr_src,
                                                   const float* __restrict__ dis,
                                                   const float* __restrict__ bias,
                                                   f16* __restrict__ out, int n) {
    int i = blockIdx.x * 4 + (threadIdx.x >> 6);
    if (i >= n) return;
    const int lane = threadIdx.x & 63;
    const int q = lane >> 4;
    const int r = lane & 15;
    float acc[8] = {};
    gather_rows(h, i, offs, csr_src, q, r, acc);
    if (q == 0) {
        float di = dis[i];
        const float4* b4 = (const float4*)bias;
        float4 bb0 = b4[r * 2], bb1 = b4[r * 2 + 1];
        float bb[8] = {bb0.x, bb0.y, bb0.z, bb0.w, bb1.x, bb1.y, bb1.z, bb1.w};
        f16x8 o;
        #pragma unroll
        for (int j = 0; j < 8; j++) {
            float v = fmaf(acc[j], di, bb[j]);
            o[j] = (f16)(v > 0.f ? v : 0.f);
        }
        *(f16x8*)(out + (size_t)i * F + r * 8) = o;
    }
}

// ---------------- layer-2 aggregate fused with mean-pool partial sums ----------------
// Same gather; relu'd fp32 row accumulated into partial[g][F] via block-combined atomics.
__global__ __launch_bounds__(256) void aggregate_pool(const f16* __restrict__ h,
                                                      const int* __restrict__ offs,
                                                      const int* __restrict__ csr_src,
                                                      const float* __restrict__ dis,
                                                      const float* __restrict__ bias,
                                                      const int* __restrict__ batch,
                                                      float* __restrict__ partial, int n) {
    const int wid = threadIdx.x >> 6;
    const int lane = threadIdx.x & 63;
    int i = blockIdx.x * 4 + wid;
    const bool valid = i < n;
    const int ii = valid ? i : (n - 1);
    const int q = lane >> 4;
    const int r = lane & 15;
    float acc[8] = {};
    gather_rows(h, ii, offs, csr_src, q, r, acc);
    __shared__ float sacc[4][128];
    __shared__ int sg[4];
    if (q == 0) {
        float di = dis[ii];
        const float4* b4 = (const float4*)bias;
        float4 bb0 = b4[r * 2], bb1 = b4[r * 2 + 1];
        float bb[8] = {bb0.x, bb0.y, bb0.z, bb0.w, bb1.x, bb1.y, bb1.z, bb1.w};
        #pragma unroll
        for (int j = 0; j < 8; j++) {
            float v = fmaf(acc[j], di, bb[j]);
            v = v > 0.f ? v : 0.f;
            sacc[wid][r * 8 + j] = valid ? v : 0.f;
        }
    }
    if (lane == 0) sg[wid] = valid ? batch[ii] : -1;
    __syncthreads();
    if (wid == 0) {
        const int f0 = lane * 2, f1 = lane * 2 + 1;
        int g0 = sg[0], g1 = sg[1], g2 = sg[2], g3 = sg[3];
        if (g0 == g1 && g1 == g2 && g2 == g3) {     // common case: one graph
            if (g0 >= 0) {
                float s0 = (sacc[0][f0] + sacc[1][f0]) + (sacc[2][f0] + sacc[3][f0]);
                float s1 = (sacc[0][f1] + sacc[1][f1]) + (sacc[2][f1] + sacc[3][f1]);
                atomicAdd(&partial[(size_t)g0 * F + f0], s0);
                atomicAdd(&partial[(size_t)g0 * F + f1], s1);
            }
        } else {                                     // graph boundary (rare)
            #pragma unroll
            for (int w = 0; w < 4; w++) {
                int g = sg[w];
                if (g >= 0) {
                    atomicAdd(&partial[(size_t)g * F + f0], sacc[w][f0]);
                    atomicAdd(&partial[(size_t)g * F + f1], sacc[w][f1]);
                }
            }
        }
    }
}

// ---------------- final: mean + linear head ----------------
__global__ __launch_bounds__(128) void pool_final(const float* __restrict__ partial,
                                                  const int* __restrict__ batch,
                                                  const float* __restrict__ Wlin,
                                                  const float* __restrict__ blin,
                                                  float* __restrict__ out, int n) {
    int g = blockIdx.x;
    int f = threadIdx.x;
    __shared__ int se[2];
    if (threadIdx.x < 2) {
        int target = g + threadIdx.x;
        int lo = 0, hi = n;
        while (lo < hi) {
            int mid = (lo + hi) >> 1;
            if (batch[mid] < target) lo = mid + 1; else hi = mid;
        }
        se[threadIdx.x] = lo;
    }
    __syncthreads();
    int s = se[0], e = se[1];
    float cnt = (float)((e - s) > 0 ? (e - s) : 1);
    float p = partial[(size_t)g * F + f] / cnt;
    float v0 = p * Wlin[f * 2 + 0];
    float v1 = p * Wlin[f * 2 + 1];
    #pragma unroll
    for (int o = 32; o > 0; o >>= 1) {
        v0 += __shfl_xor(v0, o);
        v1 += __shfl_xor(v1, o);
    }
    __shared__ float red[4];
    int wid = threadIdx.x >> 6;
    if ((threadIdx.x & 63) == 0) { red[wid * 2] = v0; red[wid * 2 + 1] = v1; }
    __syncthreads();
    if (threadIdx.x == 0) {
        out[g * 2 + 0] = red[0] + red[2] + blin[0];
        out[g * 2 + 1] = red[1] + red[3] + blin[1];
    }
}

extern "C" void kernel_launch(void* const* d_in, const int* in_sizes, int n_in,
                              void* d_out, int out_size, void* d_ws, size_t ws_size,
                              hipStream_t stream) {
    const float* X     = (const float*)d_in[0];
    const int*   ei    = (const int*)d_in[1];
    const int*   batch = (const int*)d_in[2];
    const float* W1    = (const float*)d_in[3];
    const float* b1    = (const float*)d_in[4];
    const float* W2    = (const float*)d_in[5];
    const float* b2    = (const float*)d_in[6];
    const float* Wlin  = (const float*)d_in[7];
    const float* blin  = (const float*)d_in[8];
    float* out = (float*)d_out;

    char* p = (char*)d_ws;
    auto alloc = [&](size_t bytes) -> char* {
        char* r = p;
        p += (bytes + 255) & ~size_t(255);
        return r;
    };
    int*   gcur       = (int*)alloc((size_t)NB * 4);
    int*   bucketBase = (int*)alloc((size_t)NB * 4);
    int*   offs       = (int*)alloc((size_t)(NN + 1) * 4);
    float* dis        = (float*)alloc((size_t)NN * 4);
    u32*   binned     = (u32*)alloc((size_t)NB * RCAP * 4);
    int*   csr_src    = (int*)alloc((size_t)NE * 4);
    f16*   WT1        = (f16*)alloc((size_t)128 * 128 * 2);
    f16*   WT2        = (f16*)alloc((size_t)128 * 128 * 2);
    f16*   bufA       = (f16*)alloc((size_t)NN * F * 2);
    f16*   bufB       = (f16*)alloc((size_t)NN * F * 2);
    float* partial    = (float*)alloc((size_t)NG * F * 4);

    prep_w<<<64, 256, 0, stream>>>(W1, W2, WT1, WT2, gcur);
    bin_edges<<<256, 256, 0, stream>>>(ei, gcur, binned);
    scan_buckets<<<1, 512, 0, stream>>>(gcur, bucketBase, offs);
    build_csr<<<NB, 256, 0, stream>>>(binned, gcur, bucketBase, offs, dis, csr_src);
    hipMemsetAsync(partial, 0, (size_t)NG * F * 4, stream);

    gemm_mfma<false><<<(NN + 127) / 128, 256, 0, stream>>>(X, WT1, dis, bufA, NN);
    aggregate16<<<(NN + 3) / 4, 256, 0, stream>>>(bufA, offs, csr_src, dis, b1, bufB, NN);
    gemm_mfma<true><<<(NN + 127) / 128, 256, 0, stream>>>(bufB, WT2, dis, bufA, NN);
    aggregate_pool<<<(NN + 3) / 4, 256, 0, stream>>>(bufA, offs, csr_src, dis, b2, batch, partial, NN);
    pool_final<<<NG, 128, 0, stream>>>(partial, batch, Wlin, blin, out, NN);
}

// Round 7
// 273.056 us; speedup vs baseline: 1.0324x; 1.0324x over previous
//
#include <hip/hip_runtime.h>
#include <hip/hip_bf16.h>
#include <hip/hip_fp16.h>

// GCN: x1 = relu(scatter(norm * (X@W1)[src] -> dst) + b1)
//      x2 = relu(scatter(norm * (x1@W2)[src] -> dst) + b2)
//      out = meanpool_by_graph(x2) @ Wlin + blin
// Factored norm: out[d] = dis[d]*(sum_{s in N(d)} h'[s] + h'[d]) + b,
// where h' = (X@W) row-scaled by dis (GEMM epilogue, fp16 stored).
// CSR via 2-pass LDS-write-combined bucket sort. LDS-free direct-fragment GEMM.
constexpr int NN = 100000;   // nodes
constexpr int NE = 1600000;  // edges
constexpr int NG = 512;      // graphs
constexpr int F  = 128;      // feature dim (in == hidden)

constexpr int NB   = 392;    // buckets: node bucket = dst >> 8
constexpr int RCAP = 4608;   // per-bucket region capacity (Poisson(4082) + 8 sigma)
constexpr int CAP  = 32;     // LDS staging entries per bucket
constexpr int NCH  = 8;      // pooling chunks per graph
constexpr int BINB = 512;    // bin_edges blocks

typedef _Float16 f16;
typedef f16 f16x2 __attribute__((ext_vector_type(2)));
typedef f16 f16x4 __attribute__((ext_vector_type(4)));
typedef f16 f16x8 __attribute__((ext_vector_type(8)));
typedef float f32x4 __attribute__((ext_vector_type(4)));
typedef unsigned int u32;
typedef u32 u32x4a __attribute__((ext_vector_type(4), aligned(4)));

// ---------------- W prep (+ cursor init): fp32 [k][n] -> fp16 [n][k] ----------------
__global__ void prep_w(const float* __restrict__ W1, const float* __restrict__ W2,
                       f16* __restrict__ WT1, f16* __restrict__ WT2,
                       int* __restrict__ gcur) {
    int idx = blockIdx.x * blockDim.x + threadIdx.x;
    if (idx < NB) gcur[idx] = idx * RCAP;
    if (idx < 128 * 128) {
        int n = idx >> 7, k = idx & 127;
        WT1[idx] = (f16)W1[k * 128 + n];
        WT2[idx] = (f16)W2[k * 128 + n];
    }
}

// ---------------- pass 1: bin edges by dst bucket, LDS write-combining ----------------
__global__ __launch_bounds__(256) void bin_edges(const int* __restrict__ ei,
                                                 int* __restrict__ gcur,
                                                 u32* __restrict__ binned) {
    __shared__ u32 stage[NB][CAP];   // 50 KB
    __shared__ int scnt[NB];
    for (int b = threadIdx.x; b < NB; b += 256) scnt[b] = 0;
    __syncthreads();
    const int per = NE / BINB;       // 3125
    const int e0 = blockIdx.x * per;
    for (int r = 0; r < per; r += 256) {
        int k = r + threadIdx.x;
        if (k < per) {
            int e = e0 + k;
            int s = __builtin_nontemporal_load(&ei[e]);
            int d = __builtin_nontemporal_load(&ei[NE + e]);
            int b = d >> 8;
            u32 v = ((u32)(d & 255) << 24) | (u32)s;
            int p = atomicAdd(&scnt[b], 1);
            if (p < CAP) stage[b][p] = v;   // overflow P ~ 1e-18
        }
        __syncthreads();
        for (int b2 = threadIdx.x; b2 < NB; b2 += 256) {
            int n = scnt[b2];
            if (n >= 16) {
                int f = n & ~15;
                int base = atomicAdd(&gcur[b2], f);
                const u32x4a* st4 = (const u32x4a*)&stage[b2][0];
                u32x4a* out4 = (u32x4a*)&binned[base];
                for (int j = 0; j < (f >> 2); j++) out4[j] = st4[j];
                for (int j = 0; j < n - f; j++) stage[b2][j] = stage[b2][f + j];
                scnt[b2] = n - f;
            }
        }
        __syncthreads();
    }
    for (int b2 = threadIdx.x; b2 < NB; b2 += 256) {
        int n = scnt[b2];
        if (n > 0) {
            int base = atomicAdd(&gcur[b2], n);
            for (int j = 0; j < n; j++) binned[base + j] = stage[b2][j];
        }
    }
}

// ---------------- pass 1.5: scan bucket counts -> bucket bases ----------------
__global__ void scan_buckets(const int* __restrict__ gcur, int* __restrict__ bucketBase,
                             int* __restrict__ offs) {
    __shared__ int tmp[512];
    int t = threadIdx.x;
    int c = (t < NB) ? (gcur[t] - t * RCAP) : 0;
    tmp[t] = c;
    __syncthreads();
    for (int d = 1; d < 512; d <<= 1) {
        int x = (t >= d) ? tmp[t - d] : 0;
        __syncthreads();
        tmp[t] += x;
        __syncthreads();
    }
    if (t < NB) bucketBase[t] = tmp[t] - c;
    if (t == 0) offs[NN] = NE;
}

// ---------------- pass 2: per-bucket local CSR in LDS -> coalesced writeout ----------------
__global__ __launch_bounds__(256) void build_csr(const u32* __restrict__ binned,
                                                 const int* __restrict__ gcur,
                                                 const int* __restrict__ bucketBase,
                                                 int* __restrict__ offs,
                                                 float* __restrict__ dis,
                                                 int* __restrict__ csr_src) {
    __shared__ u32 ed[RCAP];
    __shared__ u32 lcsr[RCAP];
    __shared__ int hist[256];
    __shared__ int loff[256];
    __shared__ int lcur[256];
    const int b = blockIdx.x;
    int cnt = gcur[b] - b * RCAP;
    if (cnt > RCAP) cnt = RCAP;
    const int gbase = bucketBase[b];
    const int t = threadIdx.x;
    hist[t] = 0;
    __syncthreads();
    for (int j = t; j < cnt; j += 256) {
        u32 v = __builtin_nontemporal_load(&binned[(size_t)b * RCAP + j]);
        ed[j] = v;
        atomicAdd(&hist[v >> 24], 1);
    }
    __syncthreads();
    int h = hist[t];
    loff[t] = h;
    __syncthreads();
    for (int d = 1; d < 256; d <<= 1) {
        int x = (t >= d) ? loff[t - d] : 0;
        __syncthreads();
        loff[t] += x;
        __syncthreads();
    }
    int excl = loff[t] - h;
    lcur[t] = excl;
    int node = (b << 8) + t;
    if (node < NN) {
        offs[node] = gbase + excl;
        dis[node] = rsqrtf((float)(h + 1));   // +1 self-loop
    }
    __syncthreads();
    for (int j = t; j < cnt; j += 256) {
        u32 v = ed[j];
        int p = atomicAdd(&lcur[v >> 24], 1);
        lcsr[p] = v & 0x1FFFFu;
    }
    __syncthreads();
    for (int j = t; j < cnt; j += 256) csr_src[gbase + j] = (int)lcsr[j];
}

// ---------------- LDS-free MFMA GEMM: H[M,128] = (X @ W) * dis[row] ----------------
// 4 waves/block, 128 rows/block. Fragments loaded straight from global:
// X rows have zero reuse (each row read once per block as disjoint 16B chunks);
// W (32KB) is L2-resident. No __shared__, no barriers.
template<bool IN_HALF>
__global__ __launch_bounds__(256) void gemm_direct(const void* __restrict__ Xv,
                                                   const f16* __restrict__ WT,  // [n][k]
                                                   const float* __restrict__ dis,
                                                   f16* __restrict__ H, int M) {
    const int tid = threadIdx.x;
    const int wid = tid >> 6;
    const int lane = tid & 63;
    const int row0 = blockIdx.x * 128;
    const int wrow = wid * 32;
    const int lr = lane & 15;            // row (A) / col (B) within 16
    const int lk = (lane >> 4) * 8;      // k base
    f32x4 acc[2][8] = {};
    #pragma unroll
    for (int ks = 0; ks < 4; ks++) {
        f16x8 a[2], b[8];
        #pragma unroll
        for (int mf = 0; mf < 2; mf++) {
            int row = row0 + wrow + mf * 16 + lr;
            row = row < M ? row : M - 1;   // clamp for loads; stores guarded below
            if (IN_HALF) {
                a[mf] = *(const f16x8*)((const f16*)Xv + (size_t)row * 128 + ks * 32 + lk);
            } else {
                const float* Xf = (const float*)Xv + (size_t)row * 128 + ks * 32 + lk;
                float4 v0 = *(const float4*)Xf;
                float4 v1 = *(const float4*)(Xf + 4);
                a[mf] = f16x8{(f16)v0.x, (f16)v0.y, (f16)v0.z, (f16)v0.w,
                              (f16)v1.x, (f16)v1.y, (f16)v1.z, (f16)v1.w};
            }
        }
        #pragma unroll
        for (int nf = 0; nf < 8; nf++)
            b[nf] = *(const f16x8*)(WT + (size_t)(nf * 16 + lr) * 128 + ks * 32 + lk);
        #pragma unroll
        for (int mf = 0; mf < 2; mf++)
            #pragma unroll
            for (int nf = 0; nf < 8; nf++)
                acc[mf][nf] = __builtin_amdgcn_mfma_f32_16x16x32_f16(a[mf], b[nf], acc[mf][nf], 0, 0, 0);
    }
    // C layout: col = lane&15, row = (lane>>4)*4 + reg
    const int crow = (lane >> 4) * 4;
    #pragma unroll
    for (int mf = 0; mf < 2; mf++) {
        #pragma unroll
        for (int reg = 0; reg < 4; reg++) {
            int row = row0 + wrow + mf * 16 + crow + reg;
            if (row < M) {
                float sc = dis[row];
                #pragma unroll
                for (int nf = 0; nf < 8; nf++)
                    H[(size_t)row * 128 + nf * 16 + lr] = (f16)(acc[mf][nf][reg] * sc);
            }
        }
    }
}

// ---------------- gather core: sum of neighbor rows (quarter-wave layout) ----------------
__device__ __forceinline__ void gather_rows(const f16* __restrict__ h, int i,
                                            const int* __restrict__ offs,
                                            const int* __restrict__ csr_src,
                                            int q, int r, float acc[8]) {
    if (q == 0) {  // self-loop
        f16x8 v = *(const f16x8*)(h + (size_t)i * F + r * 8);
        #pragma unroll
        for (int j = 0; j < 8; j++) acc[j] = (float)v[j];
    }
    const int s = offs[i], e = offs[i + 1];
    int t = s + q;
    for (; t + 12 < e; t += 16) {
        int sr0 = __builtin_nontemporal_load(&csr_src[t]);
        int sr1 = __builtin_nontemporal_load(&csr_src[t + 4]);
        int sr2 = __builtin_nontemporal_load(&csr_src[t + 8]);
        int sr3 = __builtin_nontemporal_load(&csr_src[t + 12]);
        f16x8 v0 = *(const f16x8*)(h + (size_t)sr0 * F + r * 8);
        f16x8 v1 = *(const f16x8*)(h + (size_t)sr1 * F + r * 8);
        f16x8 v2 = *(const f16x8*)(h + (size_t)sr2 * F + r * 8);
        f16x8 v3 = *(const f16x8*)(h + (size_t)sr3 * F + r * 8);
        #pragma unroll
        for (int j = 0; j < 8; j++)
            acc[j] += ((float)v0[j] + (float)v1[j]) + ((float)v2[j] + (float)v3[j]);
    }
    for (; t < e; t += 4) {
        int sr = __builtin_nontemporal_load(&csr_src[t]);
        f16x8 v = *(const f16x8*)(h + (size_t)sr * F + r * 8);
        #pragma unroll
        for (int j = 0; j < 8; j++) acc[j] += (float)v[j];
    }
    #pragma unroll
    for (int j = 0; j < 8; j++) {
        acc[j] += __shfl_xor(acc[j], 16);
        acc[j] += __shfl_xor(acc[j], 32);
    }
}

// ---------------- aggregate: scale + bias + relu -> fp16 out ----------------
__global__ __launch_bounds__(256) void aggregate16(const f16* __restrict__ h,
                                                   const int* __restrict__ offs,
                                                   const int* __restrict__ csr_src,
                                                   const float* __restrict__ dis,
                                                   const float* __restrict__ bias,
                                                   f16* __restrict__ out, int n) {
    int i = blockIdx.x * 4 + (threadIdx.x >> 6);
    if (i >= n) return;
    const int lane = threadIdx.x & 63;
    const int q = lane >> 4;
    const int r = lane & 15;
    float acc[8] = {};
    gather_rows(h, i, offs, csr_src, q, r, acc);
    if (q == 0) {
        float di = dis[i];
        const float4* b4 = (const float4*)bias;
        float4 bb0 = b4[r * 2], bb1 = b4[r * 2 + 1];
        float bb[8] = {bb0.x, bb0.y, bb0.z, bb0.w, bb1.x, bb1.y, bb1.z, bb1.w};
        f16x8 o;
        #pragma unroll
        for (int j = 0; j < 8; j++) {
            float v = fmaf(acc[j], di, bb[j]);
            o[j] = (f16)(v > 0.f ? v : 0.f);
        }
        *(f16x8*)(out + (size_t)i * F + r * 8) = o;
    }
}

// ---------------- pooling stage 1: 32-way parallel partial sums ----------------
__global__ __launch_bounds__(256) void pool_partial(const f16* __restrict__ x,
                                                    const int* __restrict__ batch,
                                                    float* __restrict__ partial, int n) {
    int g = blockIdx.x;
    __shared__ int se[2];
    if (threadIdx.x < 2) {
        int target = g + threadIdx.x;
        int lo = 0, hi = n;
        while (lo < hi) {
            int mid = (lo + hi) >> 1;
            if (batch[mid] < target) lo = mid + 1; else hi = mid;
        }
        se[threadIdx.x] = lo;
    }
    __syncthreads();
    int s = se[0], e = se[1];
    int wid = threadIdx.x >> 6, lane = threadIdx.x & 63;
    int slot = blockIdx.y * 4 + wid;  // 0..31
    float a0 = 0.f, a1 = 0.f;
    const f16x2* x2 = (const f16x2*)x;
    for (int i = s + slot; i < e; i += 4 * NCH) {
        f16x2 v = x2[(size_t)i * 64 + lane];
        a0 += (float)v[0];
        a1 += (float)v[1];
    }
    __shared__ float red[4][128];
    red[wid][lane * 2] = a0;
    red[wid][lane * 2 + 1] = a1;
    __syncthreads();
    if (wid == 0) {
        float s0 = red[0][lane * 2] + red[1][lane * 2] + red[2][lane * 2] + red[3][lane * 2];
        float s1 = red[0][lane * 2 + 1] + red[1][lane * 2 + 1] + red[2][lane * 2 + 1] + red[3][lane * 2 + 1];
        float2* pp = (float2*)&partial[((size_t)g * NCH + blockIdx.y) * F];
        pp[lane] = make_float2(s0, s1);
    }
}

// ---------------- pooling stage 2: final reduce + linear head ----------------
__global__ __launch_bounds__(128) void pool_final(const float* __restrict__ partial,
                                                  const int* __restrict__ batch,
                                                  const float* __restrict__ Wlin,
                                                  const float* __restrict__ blin,
                                                  float* __restrict__ out, int n) {
    int g = blockIdx.x;
    int f = threadIdx.x;
    __shared__ int se[2];
    if (threadIdx.x < 2) {
        int target = g + threadIdx.x;
        int lo = 0, hi = n;
        while (lo < hi) {
            int mid = (lo + hi) >> 1;
            if (batch[mid] < target) lo = mid + 1; else hi = mid;
        }
        se[threadIdx.x] = lo;
    }
    __syncthreads();
    int s = se[0], e = se[1];
    float acc = 0.f;
    #pragma unroll
    for (int c = 0; c < NCH; c++) acc += partial[((size_t)g * NCH + c) * F + f];
    float cnt = (float)((e - s) > 0 ? (e - s) : 1);
    float p = acc / cnt;
    float v0 = p * Wlin[f * 2 + 0];
    float v1 = p * Wlin[f * 2 + 1];
    #pragma unroll
    for (int o = 32; o > 0; o >>= 1) {
        v0 += __shfl_xor(v0, o);
        v1 += __shfl_xor(v1, o);
    }
    __shared__ float red[4];
    int wid = threadIdx.x >> 6;
    if ((threadIdx.x & 63) == 0) { red[wid * 2] = v0; red[wid * 2 + 1] = v1; }
    __syncthreads();
    if (threadIdx.x == 0) {
        out[g * 2 + 0] = red[0] + red[2] + blin[0];
        out[g * 2 + 1] = red[1] + red[3] + blin[1];
    }
}

extern "C" void kernel_launch(void* const* d_in, const int* in_sizes, int n_in,
                              void* d_out, int out_size, void* d_ws, size_t ws_size,
                              hipStream_t stream) {
    const float* X     = (const float*)d_in[0];
    const int*   ei    = (const int*)d_in[1];
    const int*   batch = (const int*)d_in[2];
    const float* W1    = (const float*)d_in[3];
    const float* b1    = (const float*)d_in[4];
    const float* W2    = (const float*)d_in[5];
    const float* b2    = (const float*)d_in[6];
    const float* Wlin  = (const float*)d_in[7];
    const float* blin  = (const float*)d_in[8];
    float* out = (float*)d_out;

    char* p = (char*)d_ws;
    auto alloc = [&](size_t bytes) -> char* {
        char* r = p;
        p += (bytes + 255) & ~size_t(255);
        return r;
    };
    int*   gcur       = (int*)alloc((size_t)NB * 4);
    int*   bucketBase = (int*)alloc((size_t)NB * 4);
    int*   offs       = (int*)alloc((size_t)(NN + 1) * 4);
    float* dis        = (float*)alloc((size_t)NN * 4);
    u32*   binned     = (u32*)alloc((size_t)NB * RCAP * 4);
    int*   csr_src    = (int*)alloc((size_t)NE * 4);
    f16*   WT1        = (f16*)alloc((size_t)128 * 128 * 2);
    f16*   WT2        = (f16*)alloc((size_t)128 * 128 * 2);
    f16*   bufA       = (f16*)alloc((size_t)NN * F * 2);
    f16*   bufB       = (f16*)alloc((size_t)NN * F * 2);
    float* partial    = (float*)alloc((size_t)NG * NCH * F * 4);

    prep_w<<<64, 256, 0, stream>>>(W1, W2, WT1, WT2, gcur);
    bin_edges<<<BINB, 256, 0, stream>>>(ei, gcur, binned);
    scan_buckets<<<1, 512, 0, stream>>>(gcur, bucketBase, offs);
    build_csr<<<NB, 256, 0, stream>>>(binned, gcur, bucketBase, offs, dis, csr_src);

    gemm_direct<false><<<(NN + 127) / 128, 256, 0, stream>>>(X, WT1, dis, bufA, NN);
    aggregate16<<<(NN + 3) / 4, 256, 0, stream>>>(bufA, offs, csr_src, dis, b1, bufB, NN);
    gemm_direct<true><<<(NN + 127) / 128, 256, 0, stream>>>(bufB, WT2, dis, bufA, NN);
    aggregate16<<<(NN + 3) / 4, 256, 0, stream>>>(bufA, offs, csr_src, dis, b2, bufB, NN);
    pool_partial<<<dim3(NG, NCH), 256, 0, stream>>>(bufB, batch, partial, NN);
    pool_final<<<NG, 128, 0, stream>>>(partial, batch, Wlin, blin, out, NN);
}

// Round 8
// 262.741 us; speedup vs baseline: 1.0730x; 1.0393x over previous
//
#include <hip/hip_runtime.h>
#include <hip/hip_bf16.h>
#include <hip/hip_fp16.h>

// GCN: x1 = relu(scatter(norm * (X@W1)[src] -> dst) + b1)
//      x2 = relu(scatter(norm * (x1@W2)[src] -> dst) + b2)
//      out = meanpool_by_graph(x2) @ Wlin + blin
// Factored norm: out[d] = dis[d]*(sum_{s in N(d)} h'[s] + h'[d]) + b,
// where h' = (X@W) row-scaled by dis (GEMM epilogue, fp16 stored).
// CSR via 2-pass LDS bucket sort. LDS-free direct-fragment GEMM.
// Independent chains co-scheduled: {bin_edges ∥ prep_w}, {build_csr ∥ gemm1}.
constexpr int NN = 100000;   // nodes
constexpr int NE = 1600000;  // edges
constexpr int NG = 512;      // graphs
constexpr int F  = 128;      // feature dim (in == hidden)

constexpr int NB   = 392;    // buckets: node bucket = dst >> 8
constexpr int RCAP = 4608;   // per-bucket region capacity (Poisson(4082) + 8 sigma)
constexpr int CAP  = 32;     // LDS staging entries per bucket
constexpr int NCH  = 8;      // pooling chunks per graph
constexpr int BINB = 512;    // bin_edges blocks
constexpr int GEMB = (NN + 127) / 128;  // gemm blocks (782)

typedef _Float16 f16;
typedef f16 f16x2 __attribute__((ext_vector_type(2)));
typedef f16 f16x4 __attribute__((ext_vector_type(4)));
typedef f16 f16x8 __attribute__((ext_vector_type(8)));
typedef float f32x4 __attribute__((ext_vector_type(4)));
typedef unsigned int u32;
typedef u32 u32x4a __attribute__((ext_vector_type(4), aligned(4)));

// ---------------- gemm core (device): H[rows 128*bid ...] = (X @ W) * dis ----------------
template<bool IN_HALF>
__device__ __forceinline__ void gemm_body(int bid, int tid,
                                          const void* __restrict__ Xv,
                                          const f16* __restrict__ WT,  // [n][k]
                                          const float* __restrict__ dis,
                                          f16* __restrict__ H, int M) {
    const int wid = tid >> 6;
    const int lane = tid & 63;
    const int row0 = bid * 128;
    const int wrow = wid * 32;
    const int lr = lane & 15;            // row (A) / col (B) within 16
    const int lk = (lane >> 4) * 8;      // k base
    f32x4 acc[2][8] = {};
    #pragma unroll
    for (int ks = 0; ks < 4; ks++) {
        f16x8 a[2], b[8];
        #pragma unroll
        for (int mf = 0; mf < 2; mf++) {
            int row = row0 + wrow + mf * 16 + lr;
            row = row < M ? row : M - 1;   // clamp for loads; stores guarded below
            if (IN_HALF) {
                a[mf] = *(const f16x8*)((const f16*)Xv + (size_t)row * 128 + ks * 32 + lk);
            } else {
                const float* Xf = (const float*)Xv + (size_t)row * 128 + ks * 32 + lk;
                float4 v0 = *(const float4*)Xf;
                float4 v1 = *(const float4*)(Xf + 4);
                a[mf] = f16x8{(f16)v0.x, (f16)v0.y, (f16)v0.z, (f16)v0.w,
                              (f16)v1.x, (f16)v1.y, (f16)v1.z, (f16)v1.w};
            }
        }
        #pragma unroll
        for (int nf = 0; nf < 8; nf++)
            b[nf] = *(const f16x8*)(WT + (size_t)(nf * 16 + lr) * 128 + ks * 32 + lk);
        #pragma unroll
        for (int mf = 0; mf < 2; mf++)
            #pragma unroll
            for (int nf = 0; nf < 8; nf++)
                acc[mf][nf] = __builtin_amdgcn_mfma_f32_16x16x32_f16(a[mf], b[nf], acc[mf][nf], 0, 0, 0);
    }
    // C layout: col = lane&15, row = (lane>>4)*4 + reg
    const int crow = (lane >> 4) * 4;
    #pragma unroll
    for (int mf = 0; mf < 2; mf++) {
        #pragma unroll
        for (int reg = 0; reg < 4; reg++) {
            int row = row0 + wrow + mf * 16 + crow + reg;
            if (row < M) {
                float sc = dis[row];
                #pragma unroll
                for (int nf = 0; nf < 8; nf++)
                    H[(size_t)row * 128 + nf * 16 + lr] = (f16)(acc[mf][nf][reg] * sc);
            }
        }
    }
}

// ---------------- K1: bin_edges(0..BINB-1) ∥ prep_w(BINB..BINB+63) ----------------
// gcur memset to 0 beforehand; bases are b*RCAP + offset.
__global__ __launch_bounds__(256) void k1_bin_prepw(const int* __restrict__ ei,
                                                    int* __restrict__ gcur,
                                                    u32* __restrict__ binned,
                                                    const float* __restrict__ W1,
                                                    const float* __restrict__ W2,
                                                    f16* __restrict__ WT1,
                                                    f16* __restrict__ WT2) {
    __shared__ u32 stage[NB][CAP];   // 50 KB
    __shared__ int scnt[NB];
    if (blockIdx.x >= BINB) {        // prep_w part
        int idx = (blockIdx.x - BINB) * 256 + threadIdx.x;
        int n = idx >> 7, k = idx & 127;
        WT1[idx] = (f16)W1[k * 128 + n];
        WT2[idx] = (f16)W2[k * 128 + n];
        return;
    }
    for (int b = threadIdx.x; b < NB; b += 256) scnt[b] = 0;
    __syncthreads();
    const int per = NE / BINB;       // 3125
    const int e0 = blockIdx.x * per;
    for (int r = 0; r < per; r += 256) {
        int k = r + threadIdx.x;
        if (k < per) {
            int e = e0 + k;
            int s = __builtin_nontemporal_load(&ei[e]);
            int d = __builtin_nontemporal_load(&ei[NE + e]);
            int b = d >> 8;
            u32 v = ((u32)(d & 255) << 24) | (u32)s;
            int p = atomicAdd(&scnt[b], 1);
            if (p < CAP) stage[b][p] = v;   // overflow P ~ 1e-18
        }
        __syncthreads();
        for (int b2 = threadIdx.x; b2 < NB; b2 += 256) {
            int n = scnt[b2];
            if (n >= 16) {
                int f = n & ~15;
                int base = b2 * RCAP + atomicAdd(&gcur[b2], f);
                const u32x4a* st4 = (const u32x4a*)&stage[b2][0];
                u32x4a* out4 = (u32x4a*)&binned[base];
                for (int j = 0; j < (f >> 2); j++) out4[j] = st4[j];
                for (int j = 0; j < n - f; j++) stage[b2][j] = stage[b2][f + j];
                scnt[b2] = n - f;
            }
        }
        __syncthreads();
    }
    for (int b2 = threadIdx.x; b2 < NB; b2 += 256) {
        int n = scnt[b2];
        if (n > 0) {
            int base = b2 * RCAP + atomicAdd(&gcur[b2], n);
            for (int j = 0; j < n; j++) binned[base + j] = stage[b2][j];
        }
    }
}

// ---------------- scan bucket counts -> bucket bases ----------------
__global__ void scan_buckets(const int* __restrict__ gcur, int* __restrict__ bucketBase,
                             int* __restrict__ offs) {
    __shared__ int tmp[512];
    int t = threadIdx.x;
    int c = (t < NB) ? gcur[t] : 0;
    tmp[t] = c;
    __syncthreads();
    for (int d = 1; d < 512; d <<= 1) {
        int x = (t >= d) ? tmp[t - d] : 0;
        __syncthreads();
        tmp[t] += x;
        __syncthreads();
    }
    if (t < NB) bucketBase[t] = tmp[t] - c;
    if (t == 0) offs[NN] = NE;
}

// ---------------- K3: build_csr(0..NB-1) ∥ gemm1(NB..NB+GEMB-1) ----------------
__global__ __launch_bounds__(256) void k3_csr_gemm1(const u32* __restrict__ binned,
                                                    const int* __restrict__ gcur,
                                                    const int* __restrict__ bucketBase,
                                                    int* __restrict__ offs,
                                                    float* __restrict__ dis,
                                                    int* __restrict__ csr_src,
                                                    const float* __restrict__ X,
                                                    const f16* __restrict__ WT1,
                                                    const float* __restrict__ degdis,
                                                    f16* __restrict__ H) {
    __shared__ u32 ed[RCAP];     // 18.4 KB
    __shared__ u32 lcsr[RCAP];   // 18.4 KB
    __shared__ int hist[256];
    __shared__ int loff[256];
    __shared__ int lcur[256];
    if (blockIdx.x >= NB) {      // gemm1 part (layer-1: fp32 input)
        gemm_body<false>(blockIdx.x - NB, threadIdx.x, X, WT1, degdis, H, NN);
        return;
    }
    const int b = blockIdx.x;
    int cnt = gcur[b];
    if (cnt > RCAP) cnt = RCAP;
    const int gbase = bucketBase[b];
    const int t = threadIdx.x;
    hist[t] = 0;
    __syncthreads();
    for (int j = t; j < cnt; j += 256) {
        u32 v = __builtin_nontemporal_load(&binned[(size_t)b * RCAP + j]);
        ed[j] = v;
        atomicAdd(&hist[v >> 24], 1);
    }
    __syncthreads();
    int h = hist[t];
    loff[t] = h;
    __syncthreads();
    for (int d = 1; d < 256; d <<= 1) {
        int x = (t >= d) ? loff[t - d] : 0;
        __syncthreads();
        loff[t] += x;
        __syncthreads();
    }
    int excl = loff[t] - h;
    lcur[t] = excl;
    int node = (b << 8) + t;
    if (node < NN) {
        offs[node] = gbase + excl;
        dis[node] = rsqrtf((float)(h + 1));   // +1 self-loop
    }
    __syncthreads();
    for (int j = t; j < cnt; j += 256) {
        u32 v = ed[j];
        int p = atomicAdd(&lcur[v >> 24], 1);
        lcsr[p] = v & 0x1FFFFu;
    }
    __syncthreads();
    for (int j = t; j < cnt; j += 256) csr_src[gbase + j] = (int)lcsr[j];
}

// NOTE: k3's gemm reads dis[] written by k3's csr blocks?? NO — it must not.
// gemm1 needs dis for its epilogue scale, but dis is produced by build_csr in
// the SAME launch (no ordering). Solution used here: gemm1 writes UNSCALED
// h rows; the dis-scale is folded into aggregate1's self-loop/gather instead?
// That breaks the factoring. Instead: compute dis EARLY from bin counts.
// -> see deg_kernel below: degree counts are known after K1 (gcur holds
//    per-bucket totals but not per-node). So we compute per-node degree in
//    scan... Actually per-node degree requires the histogram. Keep it simple:
//    gemm1 here receives degdis = a dis[] computed by a tiny kernel BEFORE K3
//    from a per-node count array filled during K1 via global atomics? That
//    costs scattered atomics again. SIMPLEST correct fix: gemm1 stores
//    unscaled, and aggregate1 applies src-side scale via csr_norm-free trick:
//    out[d] = dis[d] * ( sum_s dis[s]*h[s] + dis[d]*h[d] ).
//    The gather would need per-edge dis[s] multiply -> extra VALU + dis reads.
// To avoid all this, K3's gemm uses the PREVIOUS launch's dis? There is none.
// => Final resolution (used below): aggregate1 reads h UNSCALED and csr stores
//    pre-scaled fp16 rows? No. We simply scale h rows in a pass fused into
//    aggregate1's self-loop: self = dis^2 * h[i], neighbors need dis[s]*h[s].
//    aggregate1 therefore loads dis[sr] per edge (scalar per quarter, cached)
//    and multiplies. Cost: 1 extra smem-class load + 1 VALU per 8 floats.

// ---------------- gather core WITH per-src scale ----------------
__device__ __forceinline__ void gather_rows_scaled(const f16* __restrict__ h, int i,
                                                   const int* __restrict__ offs,
                                                   const int* __restrict__ csr_src,
                                                   const float* __restrict__ dis,
                                                   int q, int r, float acc[8]) {
    if (q == 0) {  // self-loop: dis[i]*h[i]
        f16x8 v = *(const f16x8*)(h + (size_t)i * F + r * 8);
        float di = dis[i];
        #pragma unroll
        for (int j = 0; j < 8; j++) acc[j] = (float)v[j] * di;
    }
    const int s = offs[i], e = offs[i + 1];
    int t = s + q;
    for (; t + 4 < e; t += 8) {
        int sr0 = csr_src[t];
        int sr1 = csr_src[t + 4];
        float d0 = dis[sr0], d1 = dis[sr1];
        f16x8 v0 = *(const f16x8*)(h + (size_t)sr0 * F + r * 8);
        f16x8 v1 = *(const f16x8*)(h + (size_t)sr1 * F + r * 8);
        #pragma unroll
        for (int j = 0; j < 8; j++)
            acc[j] += (float)v0[j] * d0 + (float)v1[j] * d1;
    }
    if (t < e) {
        int sr = csr_src[t];
        float d0 = dis[sr];
        f16x8 v = *(const f16x8*)(h + (size_t)sr * F + r * 8);
        #pragma unroll
        for (int j = 0; j < 8; j++) acc[j] += (float)v[j] * d0;
    }
    #pragma unroll
    for (int j = 0; j < 8; j++) {
        acc[j] += __shfl_xor(acc[j], 16);
        acc[j] += __shfl_xor(acc[j], 32);
    }
}

// ---------------- plain gather (rows already dis-scaled) ----------------
__device__ __forceinline__ void gather_rows(const f16* __restrict__ h, int i,
                                            const int* __restrict__ offs,
                                            const int* __restrict__ csr_src,
                                            int q, int r, float acc[8]) {
    if (q == 0) {
        f16x8 v = *(const f16x8*)(h + (size_t)i * F + r * 8);
        #pragma unroll
        for (int j = 0; j < 8; j++) acc[j] = (float)v[j];
    }
    const int s = offs[i], e = offs[i + 1];
    int t = s + q;
    for (; t + 4 < e; t += 8) {
        int sr0 = csr_src[t];
        int sr1 = csr_src[t + 4];
        f16x8 v0 = *(const f16x8*)(h + (size_t)sr0 * F + r * 8);
        f16x8 v1 = *(const f16x8*)(h + (size_t)sr1 * F + r * 8);
        #pragma unroll
        for (int j = 0; j < 8; j++) acc[j] += (float)v0[j] + (float)v1[j];
    }
    if (t < e) {
        int sr = csr_src[t];
        f16x8 v = *(const f16x8*)(h + (size_t)sr * F + r * 8);
        #pragma unroll
        for (int j = 0; j < 8; j++) acc[j] += (float)v[j];
    }
    #pragma unroll
    for (int j = 0; j < 8; j++) {
        acc[j] += __shfl_xor(acc[j], 16);
        acc[j] += __shfl_xor(acc[j], 32);
    }
}

// ---------------- aggregate1: per-src scaled gather + bias + relu -> fp16 ----------------
__global__ __launch_bounds__(256) void aggregate_l1(const f16* __restrict__ h,
                                                    const int* __restrict__ offs,
                                                    const int* __restrict__ csr_src,
                                                    const float* __restrict__ dis,
                                                    const float* __restrict__ bias,
                                                    f16* __restrict__ out, int n) {
    int i = blockIdx.x * 4 + (threadIdx.x >> 6);
    if (i >= n) return;
    const int lane = threadIdx.x & 63;
    const int q = lane >> 4;
    const int r = lane & 15;
    float acc[8] = {};
    gather_rows_scaled(h, i, offs, csr_src, dis, q, r, acc);
    if (q == 0) {
        float di = dis[i];
        const float4* b4 = (const float4*)bias;
        float4 bb0 = b4[r * 2], bb1 = b4[r * 2 + 1];
        float bb[8] = {bb0.x, bb0.y, bb0.z, bb0.w, bb1.x, bb1.y, bb1.z, bb1.w};
        f16x8 o;
        #pragma unroll
        for (int j = 0; j < 8; j++) {
            float v = fmaf(acc[j], di, bb[j]);
            o[j] = (f16)(v > 0.f ? v : 0.f);
        }
        *(f16x8*)(out + (size_t)i * F + r * 8) = o;
    }
}

// ---------------- aggregate2: rows pre-scaled by gemm epilogue ----------------
__global__ __launch_bounds__(256) void aggregate_l2(const f16* __restrict__ h,
                                                    const int* __restrict__ offs,
                                                    const int* __restrict__ csr_src,
                                                    const float* __restrict__ dis,
                                                    const float* __restrict__ bias,
                                                    f16* __restrict__ out, int n) {
    int i = blockIdx.x * 4 + (threadIdx.x >> 6);
    if (i >= n) return;
    const int lane = threadIdx.x & 63;
    const int q = lane >> 4;
    const int r = lane & 15;
    float acc[8] = {};
    gather_rows(h, i, offs, csr_src, q, r, acc);
    if (q == 0) {
        float di = dis[i];
        const float4* b4 = (const float4*)bias;
        float4 bb0 = b4[r * 2], bb1 = b4[r * 2 + 1];
        float bb[8] = {bb0.x, bb0.y, bb0.z, bb0.w, bb1.x, bb1.y, bb1.z, bb1.w};
        f16x8 o;
        #pragma unroll
        for (int j = 0; j < 8; j++) {
            float v = fmaf(acc[j], di, bb[j]);
            o[j] = (f16)(v > 0.f ? v : 0.f);
        }
        *(f16x8*)(out + (size_t)i * F + r * 8) = o;
    }
}

// ---------------- gemm2 standalone (input fp16, dis-scaled epilogue) ----------------
__global__ __launch_bounds__(256) void gemm2(const f16* __restrict__ Xh,
                                             const f16* __restrict__ WT,
                                             const float* __restrict__ dis,
                                             f16* __restrict__ H, int M) {
    gemm_body<true>(blockIdx.x, threadIdx.x, Xh, WT, dis, H, M);
}

// ---------------- pooling stage 1: 32-way parallel partial sums ----------------
__global__ __launch_bounds__(256) void pool_partial(const f16* __restrict__ x,
                                                    const int* __restrict__ batch,
                                                    float* __restrict__ partial, int n) {
    int g = blockIdx.x;
    __shared__ int se[2];
    if (threadIdx.x < 2) {
        int target = g + threadIdx.x;
        int lo = 0, hi = n;
        while (lo < hi) {
            int mid = (lo + hi) >> 1;
            if (batch[mid] < target) lo = mid + 1; else hi = mid;
        }
        se[threadIdx.x] = lo;
    }
    __syncthreads();
    int s = se[0], e = se[1];
    int wid = threadIdx.x >> 6, lane = threadIdx.x & 63;
    int slot = blockIdx.y * 4 + wid;  // 0..31
    float a0 = 0.f, a1 = 0.f;
    const f16x2* x2 = (const f16x2*)x;
    for (int i = s + slot; i < e; i += 4 * NCH) {
        f16x2 v = x2[(size_t)i * 64 + lane];
        a0 += (float)v[0];
        a1 += (float)v[1];
    }
    __shared__ float red[4][128];
    red[wid][lane * 2] = a0;
    red[wid][lane * 2 + 1] = a1;
    __syncthreads();
    if (wid == 0) {
        float s0 = red[0][lane * 2] + red[1][lane * 2] + red[2][lane * 2] + red[3][lane * 2];
        float s1 = red[0][lane * 2 + 1] + red[1][lane * 2 + 1] + red[2][lane * 2 + 1] + red[3][lane * 2 + 1];
        float2* pp = (float2*)&partial[((size_t)g * NCH + blockIdx.y) * F];
        pp[lane] = make_float2(s0, s1);
    }
}

// ---------------- pooling stage 2: final reduce + linear head ----------------
__global__ __launch_bounds__(128) void pool_final(const float* __restrict__ partial,
                                                  const int* __restrict__ batch,
                                                  const float* __restrict__ Wlin,
                                                  const float* __restrict__ blin,
                                                  float* __restrict__ out, int n) {
    int g = blockIdx.x;
    int f = threadIdx.x;
    __shared__ int se[2];
    if (threadIdx.x < 2) {
        int target = g + threadIdx.x;
        int lo = 0, hi = n;
        while (lo < hi) {
            int mid = (lo + hi) >> 1;
            if (batch[mid] < target) lo = mid + 1; else hi = mid;
        }
        se[threadIdx.x] = lo;
    }
    __syncthreads();
    int s = se[0], e = se[1];
    float acc = 0.f;
    #pragma unroll
    for (int c = 0; c < NCH; c++) acc += partial[((size_t)g * NCH + c) * F + f];
    float cnt = (float)((e - s) > 0 ? (e - s) : 1);
    float p = acc / cnt;
    float v0 = p * Wlin[f * 2 + 0];
    float v1 = p * Wlin[f * 2 + 1];
    #pragma unroll
    for (int o = 32; o > 0; o >>= 1) {
        v0 += __shfl_xor(v0, o);
        v1 += __shfl_xor(v1, o);
    }
    __shared__ float red[4];
    int wid = threadIdx.x >> 6;
    if ((threadIdx.x & 63) == 0) { red[wid * 2] = v0; red[wid * 2 + 1] = v1; }
    __syncthreads();
    if (threadIdx.x == 0) {
        out[g * 2 + 0] = red[0] + red[2] + blin[0];
        out[g * 2 + 1] = red[1] + red[3] + blin[1];
    }
}

extern "C" void kernel_launch(void* const* d_in, const int* in_sizes, int n_in,
                              void* d_out, int out_size, void* d_ws, size_t ws_size,
                              hipStream_t stream) {
    const float* X     = (const float*)d_in[0];
    const int*   ei    = (const int*)d_in[1];
    const int*   batch = (const int*)d_in[2];
    const float* W1    = (const float*)d_in[3];
    const float* b1    = (const float*)d_in[4];
    const float* W2    = (const float*)d_in[5];
    const float* b2    = (const float*)d_in[6];
    const float* Wlin  = (const float*)d_in[7];
    const float* blin  = (const float*)d_in[8];
    float* out = (float*)d_out;

    char* p = (char*)d_ws;
    auto alloc = [&](size_t bytes) -> char* {
        char* r = p;
        p += (bytes + 255) & ~size_t(255);
        return r;
    };
    int*   gcur       = (int*)alloc((size_t)NB * 4);
    int*   bucketBase = (int*)alloc((size_t)NB * 4);
    int*   offs       = (int*)alloc((size_t)(NN + 1) * 4);
    float* dis        = (float*)alloc((size_t)NN * 4);
    u32*   binned     = (u32*)alloc((size_t)NB * RCAP * 4);
    int*   csr_src    = (int*)alloc((size_t)NE * 4);
    f16*   WT1        = (f16*)alloc((size_t)128 * 128 * 2);
    f16*   WT2        = (f16*)alloc((size_t)128 * 128 * 2);
    f16*   bufA       = (f16*)alloc((size_t)NN * F * 2);
    f16*   bufB       = (f16*)alloc((size_t)NN * F * 2);
    float* partial    = (float*)alloc((size_t)NG * NCH * F * 4);
    float* ones       = (float*)alloc((size_t)NN * 4);  // unit scale for gemm1 epilogue

    hipMemsetAsync(gcur, 0, (size_t)NB * 4, stream);
    // ones[] = 1.0f pattern via memset is invalid; gemm1 epilogue instead uses
    // dis=nullptr semantics — simplest: small init kernel folded into K1? To
    // keep it simple and capture-safe we reuse pool_final's... -> do a tiny
    // lambda kernel here:
    // (separate 1-liner kernel)
    extern __global__ void fill_ones(float*, int);
    fill_ones<<<(NN + 255) / 256, 256, 0, stream>>>(ones, NN);

    // K1: bin_edges ∥ prep_w
    k1_bin_prepw<<<BINB + 64, 256, 0, stream>>>(ei, gcur, binned, W1, W2, WT1, WT2);
    scan_buckets<<<1, 512, 0, stream>>>(gcur, bucketBase, offs);
    // K3: build_csr ∥ gemm1 (gemm1 epilogue scale = 1.0; dis not ready yet)
    k3_csr_gemm1<<<NB + GEMB, 256, 0, stream>>>(binned, gcur, bucketBase, offs, dis,
                                                csr_src, X, WT1, ones, bufA);

    aggregate_l1<<<(NN + 3) / 4, 256, 0, stream>>>(bufA, offs, csr_src, dis, b1, bufB, NN);
    gemm2<<<GEMB, 256, 0, stream>>>(bufB, WT2, dis, bufA, NN);
    aggregate_l2<<<(NN + 3) / 4, 256, 0, stream>>>(bufA, offs, csr_src, dis, b2, bufB, NN);
    pool_partial<<<dim3(NG, NCH), 256, 0, stream>>>(bufB, batch, partial, NN);
    pool_final<<<NG, 128, 0, stream>>>(partial, batch, Wlin, blin, out, NN);
}

// tiny init kernel (definition)
__global__ void fill_ones(float* __restrict__ v, int n) {
    int i = blockIdx.x * blockDim.x + threadIdx.x;
    if (i < n) v[i] = 1.0f;
}